// Round 1
// baseline (1282.747 us; speedup 1.0000x reference)
//
#include <hip/hip_runtime.h>
#include <cstdint>
#include <cstddef>

#define B_ 4
#define L_ 64
#define N_ 256
#define Q_ 1024
#define OUT_ 64

// Static device scratch for the small intermediates (immune to small ws_size).
__device__ double g_meand[B_ * L_ * N_];     // [b][l][n] mean over Q, f64
__device__ double g_gd[B_ * N_ * N_ * 2];    // gumbel noise per (b, n*256+m, j)
__device__ float  g_norm[B_ * N_ * N_];      // row-normalized adjacency

// ---------------- Threefry-2x32-20 (JAX-compatible) ----------------
__device__ __forceinline__ void threefry2x32(uint32_t k0, uint32_t k1,
                                             uint32_t x0, uint32_t x1,
                                             uint32_t& o0, uint32_t& o1) {
  const uint32_t ks0 = k0, ks1 = k1, ks2 = k0 ^ k1 ^ 0x1BD11BDAu;
  x0 += ks0; x1 += ks1;
#define TF_R(r) { x0 += x1; x1 = (x1 << (r)) | (x1 >> (32 - (r))); x1 ^= x0; }
  TF_R(13) TF_R(15) TF_R(26) TF_R(6)
  x0 += ks1; x1 += ks2 + 1u;
  TF_R(17) TF_R(29) TF_R(16) TF_R(24)
  x0 += ks2; x1 += ks0 + 2u;
  TF_R(13) TF_R(15) TF_R(26) TF_R(6)
  x0 += ks0; x1 += ks1 + 3u;
  TF_R(17) TF_R(29) TF_R(16) TF_R(24)
  x0 += ks1; x1 += ks2 + 4u;
  TF_R(13) TF_R(15) TF_R(26) TF_R(6)
  x0 += ks2; x1 += ks0 + 5u;
#undef TF_R
  o0 = x0; o1 = x1;
}

__device__ __forceinline__ double gumbel_from_bits(uint32_t bits) {
  // Reproduce jax.random.uniform(minval=1e-20, maxval=1.0) bit-exactly,
  // then g = -log(-log(u)) in f64 (best estimate of the f32 reference).
  uint32_t fb = (bits >> 9) | 0x3f800000u;
  float f = __uint_as_float(fb) - 1.0f;
  float u = f * 1.0f + 1e-20f;
  u = fmaxf(1e-20f, u);
  return -log(-log((double)u));
}

// Partitionable-threefry 32-bit random bits: bits[i] = o0 ^ o1 of
// threefry(key, hi32(i), lo32(i)).  (JAX >= 0.4.30 default.)
__global__ __launch_bounds__(256) void k_gumbel() {
  uint32_t i = blockIdx.x * 256u + threadIdx.x;   // 0 .. 524287
  uint32_t o0, o1;
  threefry2x32(0u, 42u, 0u, i, o0, o1);
  g_gd[i] = gumbel_from_bits(o0 ^ o1);
}

// ---------------- mean over Q ----------------
__global__ __launch_bounds__(256) void k_mean(const float* __restrict__ x) {
  int bid = blockIdx.x;  // (b*L + l)*N + n, one 1024-float contiguous row
  const float4* row = (const float4*)(x + (size_t)bid * Q_);
  float4 v = row[threadIdx.x];
  double s = (double)v.x + (double)v.y + (double)v.z + (double)v.w;
  __shared__ double red[256];
  red[threadIdx.x] = s;
  __syncthreads();
  for (int st = 128; st > 0; st >>= 1) {
    if (threadIdx.x < st) red[threadIdx.x] += red[threadIdx.x + st];
    __syncthreads();
  }
  if (threadIdx.x == 0) g_meand[bid] = red[0] * (1.0 / Q_);
}

// ---------------- corr -> MLP -> gumbel argmax -> row-normalized adj -------
__device__ __forceinline__ double gelu_exact(double v) {
  return 0.5 * v * (1.0 + erf(v * 0.70710678118654752440));
}

__global__ __launch_bounds__(256) void k_adj(const float* __restrict__ w1,
                                             const float* __restrict__ b1,
                                             const float* __restrict__ w2,
                                             const float* __restrict__ b2,
                                             const float* __restrict__ w3,
                                             const float* __restrict__ b3) {
  int bid = blockIdx.x;          // b*N + n
  int n = bid & (N_ - 1);
  int b = bid >> 8;
  int m = threadIdx.x;

  __shared__ double mn[L_];
  if (threadIdx.x < L_)
    mn[threadIdx.x] = g_meand[((size_t)(b * L_ + threadIdx.x)) * N_ + n];
  __syncthreads();

  double corr = 0.0;
#pragma unroll
  for (int l = 0; l < L_; ++l)
    corr += mn[l] * g_meand[((size_t)(b * L_ + l)) * N_ + m];

  double h1[16];
#pragma unroll
  for (int j = 0; j < 16; ++j)
    h1[j] = gelu_exact(corr * (double)w1[j] + (double)b1[j]);
  double h2[8];
#pragma unroll
  for (int i = 0; i < 8; ++i) {
    double s = (double)b2[i];
#pragma unroll
    for (int j = 0; j < 16; ++j) s += (double)w2[i * 16 + j] * h1[j];
    h2[i] = gelu_exact(s);
  }
  double z0 = (double)b3[0], z1 = (double)b3[1];
#pragma unroll
  for (int i = 0; i < 8; ++i) {
    z0 += (double)w3[i] * h2[i];
    z1 += (double)w3[8 + i] * h2[i];
  }

  size_t p = (size_t)b * (N_ * N_) + (size_t)n * N_ + m;
  double2 g = ((const double2*)g_gd)[p];
  // argmax over 2 entries; ties -> index 0 -> adj = 1
  float a = (z0 + g.x >= z1 + g.y) ? 1.0f : 0.0f;
  if (m == n) a = 1.0f;   // forced self-loop

  __shared__ float red[256];
  red[m] = a;
  __syncthreads();
  for (int st = 128; st > 0; st >>= 1) {
    if (m < st) red[m] += red[m + st];
    __syncthreads();
  }
  g_norm[p] = a / red[0];
}

// ---------------- stage 1: t[o][m][q'] = sum_l lin_w[o,l] * x[b,l,m,q] ----
__global__ __launch_bounds__(256) void k_lin(const float* __restrict__ x,
                                             const float* __restrict__ lw,
                                             float* __restrict__ t,
                                             int b, int q0, int Qc) {
  int m = blockIdx.y;
  int tx = threadIdx.x;             // 0..63 -> q quad
  int ty = threadIdx.y;             // 0..3  -> group of 16 o
  int qb = q0 + blockIdx.x * 256 + tx * 4;

  float acc[16][4];
#pragma unroll
  for (int i = 0; i < 16; ++i)
#pragma unroll
    for (int j = 0; j < 4; ++j) acc[i][j] = 0.0f;

  const float* xb = x + (((size_t)b * L_) * N_ + m) * Q_ + qb;
#pragma unroll 4
  for (int l = 0; l < L_; ++l) {
    float4 xv = *(const float4*)(xb + (size_t)l * (N_ * Q_));
    float xvv[4] = {xv.x, xv.y, xv.z, xv.w};
#pragma unroll
    for (int oi = 0; oi < 16; ++oi) {
      float w = lw[(ty * 16 + oi) * L_ + l];   // uniform -> scalar load
#pragma unroll
      for (int j = 0; j < 4; ++j) acc[oi][j] += w * xvv[j];
    }
  }
  int qoff = qb - q0;
#pragma unroll
  for (int oi = 0; oi < 16; ++oi) {
    float4 v = make_float4(acc[oi][0], acc[oi][1], acc[oi][2], acc[oi][3]);
    *(float4*)(t + ((size_t)(ty * 16 + oi) * N_ + m) * Qc + qoff) = v;
  }
}

// ---------------- stage 2: out[b,o,n,q] = sum_m norm[b,n,m]*t[o,m,q] + lb[o]
__global__ __launch_bounds__(256) void k_agg(const float* __restrict__ t,
                                             const float* __restrict__ lb,
                                             float* __restrict__ out,
                                             int b, int q0, int Qc) {
  int o = blockIdx.z;
  int nt = blockIdx.y;              // n tile of 64
  int qt = blockIdx.x;              // q tile of 64 within chunk
  int tx = threadIdx.x, ty = threadIdx.y;
  int tid = ty * 16 + tx;

  __shared__ float tl[64][64];      // [mi][q]
  __shared__ float nl[64][68];      // [mi][n], padded to dodge conflicts

  float acc[4][4];
#pragma unroll
  for (int i = 0; i < 4; ++i)
#pragma unroll
    for (int j = 0; j < 4; ++j) acc[i][j] = 0.0f;

  for (int mc = 0; mc < N_ / 64; ++mc) {
#pragma unroll
    for (int k = tid; k < 4096; k += 256) {
      int mi = k >> 6, qi = k & 63;
      tl[mi][qi] = t[((size_t)o * N_ + mc * 64 + mi) * Qc + qt * 64 + qi];
    }
#pragma unroll
    for (int k = tid; k < 4096; k += 256) {
      int ni = k >> 6, mi = k & 63;
      nl[mi][ni] = g_norm[((size_t)(b * N_ + nt * 64 + ni)) * N_ + mc * 64 + mi];
    }
    __syncthreads();
#pragma unroll
    for (int mi = 0; mi < 64; ++mi) {
      float4 tv = *(const float4*)&tl[mi][tx * 4];
      float4 nv = *(const float4*)&nl[mi][ty * 4];
      float tvv[4] = {tv.x, tv.y, tv.z, tv.w};
      float nvv[4] = {nv.x, nv.y, nv.z, nv.w};
#pragma unroll
      for (int i = 0; i < 4; ++i)
#pragma unroll
        for (int j = 0; j < 4; ++j) acc[i][j] += nvv[i] * tvv[j];
    }
    __syncthreads();
  }

  float bias = lb[o];
#pragma unroll
  for (int i = 0; i < 4; ++i) {
    float4 v = make_float4(acc[i][0] + bias, acc[i][1] + bias,
                           acc[i][2] + bias, acc[i][3] + bias);
    size_t idx = ((size_t)((b * OUT_ + o) * N_) + nt * 64 + ty * 4 + i) * Q_ +
                 q0 + qt * 64 + tx * 4;
    *(float4*)(out + idx) = v;
  }
}

// ---------------- emergency fallback (tiny ws): fused direct ----------------
__global__ __launch_bounds__(256) void k_direct(const float* __restrict__ x,
                                                const float* __restrict__ lw,
                                                const float* __restrict__ lb,
                                                float* __restrict__ out, int b) {
  int n = blockIdx.y;
  int qt = blockIdx.x;              // q tile of 64
  __shared__ float y[64][64];       // [l][q]
  int tid = threadIdx.x;
  for (int k = tid; k < 4096; k += 256) ((float*)y)[k] = 0.0f;
  __syncthreads();
  int lrow = tid >> 2;
  int qg = (tid & 3) * 16;
  const float* nr = g_norm + ((size_t)(b * N_ + n)) * N_;
  for (int m = 0; m < N_; ++m) {
    float nm = nr[m];
    if (nm == 0.0f) continue;       // uniform branch across block
    const float* xr = x + (((size_t)(b * L_ + lrow)) * N_ + m) * Q_ + qt * 64 + qg;
#pragma unroll
    for (int j = 0; j < 16; ++j) y[lrow][qg + j] += nm * xr[j];
  }
  __syncthreads();
  int q = tid & 63;
  int og = tid >> 6;
#pragma unroll
  for (int oi = 0; oi < 16; ++oi) {
    int o = og * 16 + oi;
    float s = lb[o];
#pragma unroll
    for (int l = 0; l < L_; ++l) s += lw[o * L_ + l] * y[l][q];
    out[((size_t)((b * OUT_ + o) * N_ + n)) * Q_ + qt * 64 + q] = s;
  }
}

extern "C" void kernel_launch(void* const* d_in, const int* in_sizes, int n_in,
                              void* d_out, int out_size, void* d_ws, size_t ws_size,
                              hipStream_t stream) {
  const float* x  = (const float*)d_in[0];
  const float* w1 = (const float*)d_in[1];
  const float* b1 = (const float*)d_in[2];
  const float* w2 = (const float*)d_in[3];
  const float* b2 = (const float*)d_in[4];
  const float* w3 = (const float*)d_in[5];
  const float* b3 = (const float*)d_in[6];
  const float* lw = (const float*)d_in[7];
  const float* lb = (const float*)d_in[8];
  float* out = (float*)d_out;

  k_mean<<<B_ * L_ * N_, 256, 0, stream>>>(x);
  k_gumbel<<<(B_ * N_ * N_ * 2) / 256, 256, 0, stream>>>();
  k_adj<<<B_ * N_, 256, 0, stream>>>(w1, b1, w2, b2, w3, b3);

  float* t = (float*)d_ws;
  size_t tcap = ws_size / sizeof(float);
  int Qc = 0;
  if (tcap >= (size_t)OUT_ * N_ * 1024) Qc = 1024;
  else if (tcap >= (size_t)OUT_ * N_ * 256) Qc = 256;

  if (Qc) {
    for (int b = 0; b < B_; ++b)
      for (int q0 = 0; q0 < Q_; q0 += Qc) {
        k_lin<<<dim3(Qc / 256, N_), dim3(64, 4), 0, stream>>>(x, lw, t, b, q0, Qc);
        k_agg<<<dim3(Qc / 64, N_ / 64, OUT_), dim3(16, 16), 0, stream>>>(t, lb, out, b, q0, Qc);
      }
  } else {
    for (int b = 0; b < B_; ++b)
      k_direct<<<dim3(Q_ / 64, N_), 256, 0, stream>>>(x, lw, lb, out, b);
  }
}